// Round 4
// baseline (329.948 us; speedup 1.0000x reference)
//
#include <hip/hip_runtime.h>
#include <hip/hip_bf16.h>

typedef __attribute__((ext_vector_type(8))) short bf16x8;
typedef __attribute__((ext_vector_type(4))) float f32x4;

namespace {
constexpr int kC = 256;
constexpr int kN = 2048;
constexpr int kB = 4;
constexpr int kHeads = 7;
constexpr int kOC = kHeads * 64;     // 448
constexpr int kSplit = 2;
constexpr int kMChunk = kN / kSplit; // 1024
}

static __device__ __forceinline__ ushort f2bf(float f) {
    union { float f; unsigned u; } v; v.f = f;
    unsigned r = v.u + 0x7fffu + ((v.u >> 16) & 1u);
    return (ushort)(r >> 16);
}
static __device__ __forceinline__ float bf2f(ushort u) {
    union { unsigned u; float f; } v; v.u = ((unsigned)u) << 16;
    return v.f;
}
static __device__ __forceinline__ unsigned pack2bf(float a, float b) {
    union { float f; unsigned u; } x, y; x.f = a; y.f = b;
    unsigned ra = x.u + 0x7fffu + ((x.u >> 16) & 1u);
    unsigned rb = y.u + 0x7fffu + ((y.u >> 16) & 1u);
    return __builtin_amdgcn_perm(rb, ra, 0x07060302u);
}
static __device__ __forceinline__ ushort4 pack4bf(float a, float b, float c, float d) {
    ushort4 p; p.x = f2bf(a); p.y = f2bf(b); p.z = f2bf(c); p.w = f2bf(d);
    return p;
}

// ---------------- weight cast fp32 -> bf16 ----------------
__global__ __launch_bounds__(256) void cast_w_kernel(
    const float* __restrict__ Wq, const float* __restrict__ Wk,
    const float* __restrict__ Wv, const float* __restrict__ Wf,
    ushort* __restrict__ wq, ushort* __restrict__ wk,
    ushort* __restrict__ wv, ushort* __restrict__ wf)
{
    int which = blockIdx.y;
    const float* src = which == 0 ? Wq : which == 1 ? Wk : which == 2 ? Wv : Wf;
    ushort* dst      = which == 0 ? wq : which == 1 ? wk : which == 2 ? wv : wf;
    int n = (which == 3) ? kC * kOC : kC * kC;
    int i = (blockIdx.x * 256 + threadIdx.x) * 4;
    if (i < n) {
        float4 v = *(const float4*)(src + i);
        *(ushort4*)(dst + i) = pack4bf(v.x, v.y, v.z, v.w);
    }
}

// ---------------- x transpose+cast: x[b][c][n] fp32 -> xT[b][n][c] bf16 -----
__global__ __launch_bounds__(256) void transpose_kernel(
    const float* __restrict__ x, ushort* __restrict__ xT)
{
    const int nt = blockIdx.x, ct = blockIdx.y, b = blockIdx.z;
    __shared__ float T[64][65];
    const int tid = threadIdx.x;
    const float* xb = x + ((size_t)b * kC + ct * 64) * kN + nt * 64;
#pragma unroll
    for (int p = 0; p < 16; ++p) {
        int idx = p * 256 + tid;
        int cc = idx >> 6, nn = idx & 63;
        T[cc][nn] = xb[(size_t)cc * kN + nn];
    }
    __syncthreads();
    ushort* xTb = xT + ((size_t)b * kN + nt * 64) * kC + ct * 64;
#pragma unroll
    for (int p = 0; p < 4; ++p) {
        int nn = p * 16 + (tid >> 4);
        int c4 = (tid & 15) * 4;
        *(ushort4*)&xTb[(size_t)nn * kC + c4] =
            pack4bf(T[c4 + 0][nn], T[c4 + 1][nn], T[c4 + 2][nn], T[c4 + 3][nn]);
    }
}

// ---------------- QKV projection, bf16 MFMA, coalesced stores --------------
// mat<2 (q,k): A=W (rows o), B=xT (rows n) -> acc=D[o][n]; store qT[n][o]
// mat==2 (v):  A=xT (rows n), B=W (rows o) -> acc=D[n][o]; store v[o][n]
// Epilogue: affine+relu, pack bf16x4 along minor axis, LDS gather, 16B stores.
__global__ __launch_bounds__(128) void qkv_kernel(
    const ushort* __restrict__ xT,
    const ushort* __restrict__ Wqb, const ushort* __restrict__ Wkb, const ushort* __restrict__ Wvb,
    const float* __restrict__ sq, const float* __restrict__ bq,
    const float* __restrict__ sk, const float* __restrict__ bk,
    const float* __restrict__ sv, const float* __restrict__ bv,
    ushort* __restrict__ qT, ushort* __restrict__ kT, ushort* __restrict__ vB)
{
    const int nt  = blockIdx.x;
    const int ot  = blockIdx.y;
    const int b   = blockIdx.z / 3;
    const int mat = blockIdx.z % 3;
    const ushort* Wb = mat == 0 ? Wqb : mat == 1 ? Wkb : Wvb;
    const float* sm = mat == 0 ? sq : mat == 1 ? sk : sv;
    const float* bm = mat == 0 ? bq : mat == 1 ? bk : bv;

    __shared__ __align__(16) ushort sW[64 * 64];
    __shared__ __align__(16) ushort sX[64 * 64];

    const int tid = threadIdx.x;
    const int lane = tid & 63, wav = tid >> 6;
    const int quad = lane >> 4, l16 = lane & 15;

    const ushort* xTb = xT + ((size_t)b * kN + nt * 64) * kC;
    const ushort* Wt  = Wb + (size_t)(ot * 64) * kC;

    f32x4 acc[4][2];
#pragma unroll
    for (int mt = 0; mt < 4; ++mt)
#pragma unroll
        for (int ntt = 0; ntt < 2; ++ntt)
#pragma unroll
            for (int r = 0; r < 4; ++r) acc[mt][ntt][r] = 0.f;

    for (int k0 = 0; k0 < kC; k0 += 64) {
        __syncthreads();
#pragma unroll
        for (int p = 0; p < 4; ++p) {
            int idx = p * 128 + tid;
            int row = idx >> 3, blk = idx & 7;
            *(int4*)&sW[row * 64 + ((blk ^ (row & 7)) * 8)] =
                *(const int4*)(Wt + (size_t)row * kC + k0 + blk * 8);
            *(int4*)&sX[row * 64 + ((blk ^ (row & 7)) * 8)] =
                *(const int4*)(xTb + (size_t)row * kC + k0 + blk * 8);
        }
        __syncthreads();
        const ushort* rowB = (mat < 2) ? sW : sX;  // A operand (reg axis)
        const ushort* colB = (mat < 2) ? sX : sW;  // B operand (l16 axis)
#pragma unroll
        for (int ks = 0; ks < 2; ++ks) {
            bf16x8 bfr[2];
#pragma unroll
            for (int ntt = 0; ntt < 2; ++ntt) {
                int row = wav * 32 + ntt * 16 + l16;
                bfr[ntt] = *(const bf16x8*)&colB[row * 64 + (((ks * 4 + quad) ^ (row & 7)) * 8)];
            }
#pragma unroll
            for (int mt = 0; mt < 4; ++mt) {
                int row = mt * 16 + l16;
                bf16x8 af = *(const bf16x8*)&rowB[row * 64 + (((ks * 4 + quad) ^ (row & 7)) * 8)];
#pragma unroll
                for (int ntt = 0; ntt < 2; ++ntt)
                    acc[mt][ntt] = __builtin_amdgcn_mfma_f32_16x16x32_bf16(
                        af, bfr[ntt], acc[mt][ntt], 0, 0, 0);
            }
        }
    }

    __syncthreads();            // all MFMA reads of sW done before reuse
    ushort* sT = sW;            // 64x64 bf16 transpose buffer

    if (mat < 2) {
        // acc = D[o = mt*16+quad*4+r][n = wav*32+ntt*16+l16]
#pragma unroll
        for (int mt = 0; mt < 4; ++mt) {
            float4 sc4 = *(const float4*)&sm[ot * 64 + mt * 16 + quad * 4];
            float4 bi4 = *(const float4*)&bm[ot * 64 + mt * 16 + quad * 4];
#pragma unroll
            for (int ntt = 0; ntt < 2; ++ntt) {
                int nrow = wav * 32 + ntt * 16 + l16;
                float v0 = fmaf(acc[mt][ntt][0], sc4.x, bi4.x);
                float v1 = fmaf(acc[mt][ntt][1], sc4.y, bi4.y);
                float v2 = fmaf(acc[mt][ntt][2], sc4.z, bi4.z);
                float v3 = fmaf(acc[mt][ntt][3], sc4.w, bi4.w);
                int cb = (mt * 2 + (quad >> 1)) ^ (nrow & 7);
                *(ushort4*)&sT[nrow * 64 + cb * 8 + (quad & 1) * 4] =
                    pack4bf(v0 > 0.f ? v0 : 0.f, v1 > 0.f ? v1 : 0.f,
                            v2 > 0.f ? v2 : 0.f, v3 > 0.f ? v3 : 0.f);
            }
        }
        __syncthreads();
        ushort* out = (mat == 0) ? qT : kT;
        int rsub = tid >> 3, blk = tid & 7;
#pragma unroll
        for (int p = 0; p < 4; ++p) {
            int row = p * 16 + rsub;   // n_local
            int4 d = *(const int4*)&sT[row * 64 + ((blk ^ (row & 7)) * 8)];
            *(int4*)&out[((size_t)b * kN + nt * 64 + row) * kC + ot * 64 + blk * 8] = d;
        }
    } else {
        // acc = D[n = mt*16+quad*4+r][o = wav*32+ntt*16+l16]
#pragma unroll
        for (int ntt = 0; ntt < 2; ++ntt) {
            int orow = wav * 32 + ntt * 16 + l16;
            float sc = sm[ot * 64 + orow], bi = bm[ot * 64 + orow];
#pragma unroll
            for (int mt = 0; mt < 4; ++mt) {
                float v0 = fmaf(acc[mt][ntt][0], sc, bi);
                float v1 = fmaf(acc[mt][ntt][1], sc, bi);
                float v2 = fmaf(acc[mt][ntt][2], sc, bi);
                float v3 = fmaf(acc[mt][ntt][3], sc, bi);
                int cb = (mt * 2 + (quad >> 1)) ^ (orow & 7);
                *(ushort4*)&sT[orow * 64 + cb * 8 + (quad & 1) * 4] =
                    pack4bf(v0 > 0.f ? v0 : 0.f, v1 > 0.f ? v1 : 0.f,
                            v2 > 0.f ? v2 : 0.f, v3 > 0.f ? v3 : 0.f);
            }
        }
        __syncthreads();
        int rsub = tid >> 3, blk = tid & 7;
#pragma unroll
        for (int p = 0; p < 4; ++p) {
            int row = p * 16 + rsub;   // o_local
            int4 d = *(const int4*)&sT[row * 64 + ((blk ^ (row & 7)) * 8)];
            *(int4*)&vB[((size_t)b * kC + ot * 64 + row) * kN + nt * 64 + blk * 8] = d;
        }
    }
}

// ---------------- MFMA flash attention, split-K over m ---------------------
__global__ __launch_bounds__(128) void attn_kernel(
    const ushort* __restrict__ qT, const ushort* __restrict__ kT,
    const ushort* __restrict__ vB,
    ushort* __restrict__ Opart, float* __restrict__ Ms, float* __restrict__ Ls)
{
    const int n0 = blockIdx.x * 64;
    const int h  = blockIdx.y;
    const int s  = blockIdx.z & 1;
    const int b  = blockIdx.z >> 1;
    const int tid = threadIdx.x;
    const int lane = tid & 63, wav = tid >> 6;
    const int quad = lane >> 4, l16 = lane & 15;

    __shared__ __align__(16) ushort sKP[64 * 64]; // K tile -> P tile -> O-transpose
    __shared__ __align__(16) ushort sV[64 * 64];

    const ushort* qTb = qT + (size_t)b * kN * kC;
    const ushort* kTb = kT + (size_t)b * kN * kC;
    const ushort* vbb = vB + ((size_t)b * kC + h * 32) * kN;

    bf16x8 qf[2][2];
#pragma unroll
    for (int kk = 0; kk < 2; ++kk)
#pragma unroll
        for (int nt2 = 0; nt2 < 2; ++nt2) {
            int ng = n0 + wav * 32 + nt2 * 16 + l16;
            qf[kk][nt2] = *(const bf16x8*)(qTb + (size_t)ng * kC + h * 32 + kk * 32 + quad * 8);
        }

    f32x4 oacc[4][2];
#pragma unroll
    for (int wt = 0; wt < 4; ++wt)
#pragma unroll
        for (int nt2 = 0; nt2 < 2; ++nt2)
#pragma unroll
            for (int r = 0; r < 4; ++r) oacc[wt][nt2][r] = 0.f;
    float mi[2] = {-1e30f, -1e30f};
    float li[2] = {0.f, 0.f};

    const int mstart = s * kMChunk;
    int4 kreg[4], vreg[4];
#pragma unroll
    for (int p = 0; p < 4; ++p) {
        int idx = p * 128 + tid, row = idx >> 3, blk = idx & 7;
        kreg[p] = *(const int4*)(kTb + (size_t)(mstart + row) * kC + h * 32 + blk * 8);
        vreg[p] = *(const int4*)(vbb + (size_t)row * kN + mstart + blk * 8);
    }

    for (int it = 0; it < kMChunk / 64; ++it) {
        __syncthreads();
#pragma unroll
        for (int p = 0; p < 4; ++p) {
            int idx = p * 128 + tid, row = idx >> 3, blk = idx & 7;
            *(int4*)&sKP[row * 64 + ((blk ^ (row & 7)) * 8)] = kreg[p];
            *(int4*)&sV [row * 64 + ((blk ^ (row & 7)) * 8)] = vreg[p];
        }
        if (it + 1 < kMChunk / 64) {
            int m1 = mstart + (it + 1) * 64;
#pragma unroll
            for (int p = 0; p < 4; ++p) {
                int idx = p * 128 + tid, row = idx >> 3, blk = idx & 7;
                kreg[p] = *(const int4*)(kTb + (size_t)(m1 + row) * kC + h * 32 + blk * 8);
                vreg[p] = *(const int4*)(vbb + (size_t)row * kN + m1 + blk * 8);
            }
        }
        __syncthreads();

        f32x4 sacc[4][2];
#pragma unroll
        for (int mt = 0; mt < 4; ++mt)
#pragma unroll
            for (int nt2 = 0; nt2 < 2; ++nt2)
#pragma unroll
                for (int r = 0; r < 4; ++r) sacc[mt][nt2][r] = 0.f;
#pragma unroll
        for (int kk = 0; kk < 2; ++kk)
#pragma unroll
            for (int mt = 0; mt < 4; ++mt) {
                int row = mt * 16 + l16;
                bf16x8 af = *(const bf16x8*)&sKP[row * 64 + (((kk * 4 + quad) ^ (row & 7)) * 8)];
#pragma unroll
                for (int nt2 = 0; nt2 < 2; ++nt2)
                    sacc[mt][nt2] = __builtin_amdgcn_mfma_f32_16x16x32_bf16(
                        af, qf[kk][nt2], sacc[mt][nt2], 0, 0, 0);
            }
        __syncthreads();

#pragma unroll
        for (int nt2 = 0; nt2 < 2; ++nt2) {
            float mloc = -1e30f;
#pragma unroll
            for (int mt = 0; mt < 4; ++mt)
#pragma unroll
                for (int r = 0; r < 4; ++r) mloc = fmaxf(mloc, sacc[mt][nt2][r]);
            mloc = fmaxf(mloc, __shfl_xor(mloc, 16));
            mloc = fmaxf(mloc, __shfl_xor(mloc, 32));
            float mnew = fmaxf(mi[nt2], mloc);
            float al = __expf(mi[nt2] - mnew);
            mi[nt2] = mnew;
            int nrow = wav * 32 + nt2 * 16 + l16;
            float sum = 0.f;
#pragma unroll
            for (int mt = 0; mt < 4; ++mt) {
                float p0 = __expf(sacc[mt][nt2][0] - mnew);
                float p1 = __expf(sacc[mt][nt2][1] - mnew);
                float p2 = __expf(sacc[mt][nt2][2] - mnew);
                float p3 = __expf(sacc[mt][nt2][3] - mnew);
                sum += (p0 + p1) + (p2 + p3);
                int bidx = (mt * 2 + (quad >> 1)) ^ (nrow & 7);
                uint2 pk; pk.x = pack2bf(p0, p1); pk.y = pack2bf(p2, p3);
                *(uint2*)&sKP[nrow * 64 + bidx * 8 + (quad & 1) * 4] = pk;
            }
            sum += __shfl_xor(sum, 16);
            sum += __shfl_xor(sum, 32);
            li[nt2] = li[nt2] * al + sum;
#pragma unroll
            for (int wt = 0; wt < 4; ++wt)
#pragma unroll
                for (int r = 0; r < 4; ++r) oacc[wt][nt2][r] *= al;
        }

#pragma unroll
        for (int ks = 0; ks < 2; ++ks) {
            bf16x8 pf[2];
#pragma unroll
            for (int nt2 = 0; nt2 < 2; ++nt2) {
                int nr = wav * 32 + nt2 * 16 + l16;
                pf[nt2] = *(const bf16x8*)&sKP[nr * 64 + (((ks * 4 + quad) ^ (nr & 7)) * 8)];
            }
#pragma unroll
            for (int wt = 0; wt < 4; ++wt) {
                int wr = wt * 16 + l16;
                bf16x8 vf = *(const bf16x8*)&sV[wr * 64 + (((ks * 4 + quad) ^ (wr & 7)) * 8)];
#pragma unroll
                for (int nt2 = 0; nt2 < 2; ++nt2)
                    oacc[wt][nt2] = __builtin_amdgcn_mfma_f32_16x16x32_bf16(
                        vf, pf[nt2], oacc[wt][nt2], 0, 0, 0);
            }
        }
    }

    // ---- epilogue: stats, then LDS-transpose O and store coalesced ----
#pragma unroll
    for (int nt2 = 0; nt2 < 2; ++nt2) {
        if (quad == 0) {
            int n = n0 + wav * 32 + nt2 * 16 + l16;
            size_t si = ((size_t)(s * kB + b) * kHeads + h) * kN + n;
            Ms[si] = mi[nt2];
            Ls[si] = li[nt2];
        }
    }
    __syncthreads();            // PV reads of sKP done
    ushort* sT = sKP;
#pragma unroll
    for (int wt = 0; wt < 4; ++wt)
#pragma unroll
        for (int nt2 = 0; nt2 < 2; ++nt2) {
            float inv = 1.f / li[nt2];
            int nrow = wav * 32 + nt2 * 16 + l16;
            int cb = (wt * 2 + (quad >> 1)) ^ (nrow & 7);
            *(ushort4*)&sT[nrow * 64 + cb * 8 + (quad & 1) * 4] =
                pack4bf(oacc[wt][nt2][0] * inv, oacc[wt][nt2][1] * inv,
                        oacc[wt][nt2][2] * inv, oacc[wt][nt2][3] * inv);
        }
    __syncthreads();
    int rsub = tid >> 3, blk = tid & 7;
#pragma unroll
    for (int p = 0; p < 4; ++p) {
        int row = p * 16 + rsub;   // n_local
        int4 d = *(const int4*)&sT[row * 64 + ((blk ^ (row & 7)) * 8)];
        *(int4*)&Opart[((size_t)s * kB * kN + (size_t)b * kN + n0 + row) * kOC
                       + h * 64 + blk * 8] = d;
    }
}

// ---------------- combine splits -> OT[b][n][c] bf16 -----------------------
__global__ __launch_bounds__(256) void combine_kernel(
    const ushort* __restrict__ Opart, const float* __restrict__ Ms,
    const float* __restrict__ Ls, ushort* __restrict__ OT)
{
    int t = blockIdx.x * 256 + threadIdx.x;
    int bn = t / 112;
    int c4 = (t % 112) * 4;
    int h  = c4 >> 6;
    int b = bn >> 11, n = bn & 2047;
    size_t si = ((size_t)b * kHeads + h) * kN + n;
    size_t soff = (size_t)kB * kHeads * kN;
    float m1 = Ms[si], m2 = Ms[si + soff];
    float l1 = Ls[si], l2 = Ls[si + soff];
    float M = fmaxf(m1, m2);
    float g1 = l1 * __expf(m1 - M), g2 = l2 * __expf(m2 - M);
    float inv = 1.f / (g1 + g2);
    float w1 = g1 * inv, w2 = g2 * inv;
    size_t o1 = (size_t)bn * kOC + c4;
    size_t o2 = o1 + (size_t)kB * kN * kOC;
    ushort4 a = *(const ushort4*)&Opart[o1];
    ushort4 c = *(const ushort4*)&Opart[o2];
    *(ushort4*)&OT[(size_t)bn * kOC + c4] =
        pack4bf(bf2f(a.x) * w1 + bf2f(c.x) * w2, bf2f(a.y) * w1 + bf2f(c.y) * w2,
                bf2f(a.z) * w1 + bf2f(c.z) * w2, bf2f(a.w) * w1 + bf2f(c.w) * w2);
}

// ---------------- final projection, bf16 MFMA ------------------------------
__global__ __launch_bounds__(128) void proj_kernel(
    const ushort* __restrict__ OT, const ushort* __restrict__ Wfb,
    const float* __restrict__ bf_, const float* __restrict__ sf,
    const float* __restrict__ bff, float* __restrict__ out)
{
    const int nt = blockIdx.x;
    const int ot = blockIdx.y;
    const int b  = blockIdx.z;
    __shared__ __align__(16) ushort sA[64 * 64];
    __shared__ __align__(16) ushort sB[64 * 64];
    const int tid = threadIdx.x;
    const int lane = tid & 63, wav = tid >> 6;
    const int quad = lane >> 4, l16 = lane & 15;

    const ushort* Wt = Wfb + (size_t)(ot * 64) * kOC;
    const ushort* Ob = OT + ((size_t)b * kN + nt * 64) * kOC;

    f32x4 acc[4][2];
#pragma unroll
    for (int mt = 0; mt < 4; ++mt)
#pragma unroll
        for (int ntt = 0; ntt < 2; ++ntt)
#pragma unroll
            for (int r = 0; r < 4; ++r) acc[mt][ntt][r] = 0.f;

    for (int k0 = 0; k0 < kOC; k0 += 64) {
        __syncthreads();
#pragma unroll
        for (int p = 0; p < 4; ++p) {
            int idx = p * 128 + tid;
            int row = idx >> 3, blk = idx & 7;
            *(int4*)&sA[row * 64 + ((blk ^ (row & 7)) * 8)] =
                *(const int4*)(Wt + (size_t)row * kOC + k0 + blk * 8);
            *(int4*)&sB[row * 64 + ((blk ^ (row & 7)) * 8)] =
                *(const int4*)(Ob + (size_t)row * kOC + k0 + blk * 8);
        }
        __syncthreads();
#pragma unroll
        for (int ks = 0; ks < 2; ++ks) {
            bf16x8 bfr[2];
#pragma unroll
            for (int ntt = 0; ntt < 2; ++ntt) {
                int row = wav * 32 + ntt * 16 + l16;
                bfr[ntt] = *(const bf16x8*)&sB[row * 64 + (((ks * 4 + quad) ^ (row & 7)) * 8)];
            }
#pragma unroll
            for (int mt = 0; mt < 4; ++mt) {
                int row = mt * 16 + l16;
                bf16x8 af = *(const bf16x8*)&sA[row * 64 + (((ks * 4 + quad) ^ (row & 7)) * 8)];
#pragma unroll
                for (int ntt = 0; ntt < 2; ++ntt)
                    acc[mt][ntt] = __builtin_amdgcn_mfma_f32_16x16x32_bf16(
                        af, bfr[ntt], acc[mt][ntt], 0, 0, 0);
            }
        }
    }
#pragma unroll
    for (int mt = 0; mt < 4; ++mt)
#pragma unroll
        for (int r = 0; r < 4; ++r) {
            int o = ot * 64 + mt * 16 + quad * 4 + r;
            float bfv = bf_[o], sfv = sf[o], bffv = bff[o];
#pragma unroll
            for (int ntt = 0; ntt < 2; ++ntt) {
                int n = nt * 64 + wav * 32 + ntt * 16 + l16;
                float y = fmaf(acc[mt][ntt][r] + bfv, sfv, bffv);
                out[((size_t)b * kC + o) * kN + n] = y > 0.f ? y : 0.f;
            }
        }
}

extern "C" void kernel_launch(void* const* d_in, const int* in_sizes, int n_in,
                              void* d_out, int out_size, void* d_ws, size_t ws_size,
                              hipStream_t stream) {
    const float* x   = (const float*)d_in[0];
    const float* Wq  = (const float*)d_in[1];
    const float* sq  = (const float*)d_in[2];
    const float* bq  = (const float*)d_in[3];
    const float* Wk  = (const float*)d_in[4];
    const float* sk  = (const float*)d_in[5];
    const float* bk  = (const float*)d_in[6];
    const float* Wv  = (const float*)d_in[7];
    const float* sv  = (const float*)d_in[8];
    const float* bv  = (const float*)d_in[9];
    const float* Wf  = (const float*)d_in[10];
    const float* bf_ = (const float*)d_in[11];
    const float* sf  = (const float*)d_in[12];
    const float* bff = (const float*)d_in[13];
    float* out = (float*)d_out;

    char* ws = (char*)d_ws;
    ushort* xT  = (ushort*)(ws);                         // 4,194,304
    ushort* Wqb = (ushort*)(ws + 4194304);               // 131,072
    ushort* Wkb = (ushort*)(ws + 4325376);               // 131,072
    ushort* Wvb = (ushort*)(ws + 4456448);               // 131,072
    ushort* Wfb = (ushort*)(ws + 4587520);               // 229,376
    ushort* qT  = (ushort*)(ws + 4816896);               // 4,194,304
    ushort* kT  = (ushort*)(ws + 9011200);               // 4,194,304
    ushort* vB  = (ushort*)(ws + 13205504);              // 4,194,304
    ushort* Opart = (ushort*)(ws + 17399808);            // 14,680,064
    float*  Ms  = (float*)(ws + 32079872);               // 458,752
    float*  Ls  = (float*)(ws + 32538624);               // 458,752
    ushort* OT  = qT;  // alias: qT/kT dead after attn

    cast_w_kernel<<<dim3(112, 4), 256, 0, stream>>>(Wq, Wk, Wv, Wf, Wqb, Wkb, Wvb, Wfb);
    transpose_kernel<<<dim3(kN / 64, kC / 64, kB), 256, 0, stream>>>(x, xT);
    qkv_kernel<<<dim3(kN / 64, kC / 64, kB * 3), 128, 0, stream>>>(
        xT, Wqb, Wkb, Wvb, sq, bq, sk, bk, sv, bv, qT, kT, vB);
    attn_kernel<<<dim3(kN / 64, kHeads, kB * kSplit), 128, 0, stream>>>(
        qT, kT, vB, Opart, Ms, Ls);
    combine_kernel<<<dim3(kB * kN * 112 / 256), 256, 0, stream>>>(Opart, Ms, Ls, OT);
    proj_kernel<<<dim3(kN / 64, kC / 64, kB), 128, 0, stream>>>(
        OT, Wfb, bf_, sf, bff, out);
}

// Round 5
// 209.157 us; speedup vs baseline: 1.5775x; 1.5775x over previous
//
#include <hip/hip_runtime.h>
#include <hip/hip_bf16.h>

typedef __attribute__((ext_vector_type(8))) short bf16x8;
typedef __attribute__((ext_vector_type(4))) float f32x4;

namespace {
constexpr int kC = 256;
constexpr int kN = 2048;
constexpr int kB = 4;
constexpr int kHeads = 7;
constexpr int kOC = kHeads * 64;     // 448
constexpr int kSplit = 2;
constexpr int kMChunk = kN / kSplit; // 1024
}

static __device__ __forceinline__ ushort f2bf(float f) {
    union { float f; unsigned u; } v; v.f = f;
    unsigned r = v.u + 0x7fffu + ((v.u >> 16) & 1u);
    return (ushort)(r >> 16);
}
static __device__ __forceinline__ float bf2f(ushort u) {
    union { unsigned u; float f; } v; v.u = ((unsigned)u) << 16;
    return v.f;
}
static __device__ __forceinline__ unsigned pack2bf(float a, float b) {
    union { float f; unsigned u; } x, y; x.f = a; y.f = b;
    unsigned ra = x.u + 0x7fffu + ((x.u >> 16) & 1u);
    unsigned rb = y.u + 0x7fffu + ((y.u >> 16) & 1u);
    return __builtin_amdgcn_perm(rb, ra, 0x07060302u);
}
static __device__ __forceinline__ ushort4 pack4bf(float a, float b, float c, float d) {
    ushort4 p; p.x = f2bf(a); p.y = f2bf(b); p.z = f2bf(c); p.w = f2bf(d);
    return p;
}

// ---------------- weight cast fp32 -> bf16 ----------------
__global__ __launch_bounds__(256) void cast_w_kernel(
    const float* __restrict__ Wq, const float* __restrict__ Wk,
    const float* __restrict__ Wv, const float* __restrict__ Wf,
    ushort* __restrict__ wq, ushort* __restrict__ wk,
    ushort* __restrict__ wv, ushort* __restrict__ wf)
{
    int which = blockIdx.y;
    const float* src = which == 0 ? Wq : which == 1 ? Wk : which == 2 ? Wv : Wf;
    ushort* dst      = which == 0 ? wq : which == 1 ? wk : which == 2 ? wv : wf;
    int n = (which == 3) ? kC * kOC : kC * kC;
    int i = (blockIdx.x * 256 + threadIdx.x) * 4;
    if (i < n) {
        float4 v = *(const float4*)(src + i);
        *(ushort4*)(dst + i) = pack4bf(v.x, v.y, v.z, v.w);
    }
}

// ---------------- x transpose+cast: x[b][c][n] fp32 -> xT[b][n][c] bf16 -----
__global__ __launch_bounds__(256) void transpose_kernel(
    const float* __restrict__ x, ushort* __restrict__ xT)
{
    const int nt = blockIdx.x, ct = blockIdx.y, b = blockIdx.z;
    __shared__ float T[64][65];
    const int tid = threadIdx.x;
    const float* xb = x + ((size_t)b * kC + ct * 64) * kN + nt * 64;
#pragma unroll
    for (int p = 0; p < 16; ++p) {
        int idx = p * 256 + tid;
        int cc = idx >> 6, nn = idx & 63;
        T[cc][nn] = xb[(size_t)cc * kN + nn];
    }
    __syncthreads();
    ushort* xTb = xT + ((size_t)b * kN + nt * 64) * kC + ct * 64;
#pragma unroll
    for (int p = 0; p < 4; ++p) {
        int nn = p * 16 + (tid >> 4);
        int c4 = (tid & 15) * 4;
        *(ushort4*)&xTb[(size_t)nn * kC + c4] =
            pack4bf(T[c4 + 0][nn], T[c4 + 1][nn], T[c4 + 2][nn], T[c4 + 3][nn]);
    }
}

// ---------------- QKV projection, bf16 MFMA, coalesced stores --------------
__global__ __launch_bounds__(128) void qkv_kernel(
    const ushort* __restrict__ xT,
    const ushort* __restrict__ Wqb, const ushort* __restrict__ Wkb, const ushort* __restrict__ Wvb,
    const float* __restrict__ sq, const float* __restrict__ bq,
    const float* __restrict__ sk, const float* __restrict__ bk,
    const float* __restrict__ sv, const float* __restrict__ bv,
    ushort* __restrict__ qT, ushort* __restrict__ kT, ushort* __restrict__ vB)
{
    const int nt  = blockIdx.x;
    const int ot  = blockIdx.y;
    const int b   = blockIdx.z / 3;
    const int mat = blockIdx.z % 3;
    const ushort* Wb = mat == 0 ? Wqb : mat == 1 ? Wkb : Wvb;
    const float* sm = mat == 0 ? sq : mat == 1 ? sk : sv;
    const float* bm = mat == 0 ? bq : mat == 1 ? bk : bv;

    __shared__ __align__(16) ushort sW[64 * 64];
    __shared__ __align__(16) ushort sX[64 * 64];

    const int tid = threadIdx.x;
    const int lane = tid & 63, wav = tid >> 6;
    const int quad = lane >> 4, l16 = lane & 15;

    const ushort* xTb = xT + ((size_t)b * kN + nt * 64) * kC;
    const ushort* Wt  = Wb + (size_t)(ot * 64) * kC;

    f32x4 acc[4][2];
#pragma unroll
    for (int mt = 0; mt < 4; ++mt)
#pragma unroll
        for (int ntt = 0; ntt < 2; ++ntt)
#pragma unroll
            for (int r = 0; r < 4; ++r) acc[mt][ntt][r] = 0.f;

    for (int k0 = 0; k0 < kC; k0 += 64) {
        __syncthreads();
#pragma unroll
        for (int p = 0; p < 4; ++p) {
            int idx = p * 128 + tid;
            int row = idx >> 3, blk = idx & 7;
            *(int4*)&sW[row * 64 + ((blk ^ (row & 7)) * 8)] =
                *(const int4*)(Wt + (size_t)row * kC + k0 + blk * 8);
            *(int4*)&sX[row * 64 + ((blk ^ (row & 7)) * 8)] =
                *(const int4*)(xTb + (size_t)row * kC + k0 + blk * 8);
        }
        __syncthreads();
        const ushort* rowB = (mat < 2) ? sW : sX;
        const ushort* colB = (mat < 2) ? sX : sW;
#pragma unroll
        for (int ks = 0; ks < 2; ++ks) {
            bf16x8 bfr[2];
#pragma unroll
            for (int ntt = 0; ntt < 2; ++ntt) {
                int row = wav * 32 + ntt * 16 + l16;
                bfr[ntt] = *(const bf16x8*)&colB[row * 64 + (((ks * 4 + quad) ^ (row & 7)) * 8)];
            }
#pragma unroll
            for (int mt = 0; mt < 4; ++mt) {
                int row = mt * 16 + l16;
                bf16x8 af = *(const bf16x8*)&rowB[row * 64 + (((ks * 4 + quad) ^ (row & 7)) * 8)];
#pragma unroll
                for (int ntt = 0; ntt < 2; ++ntt)
                    acc[mt][ntt] = __builtin_amdgcn_mfma_f32_16x16x32_bf16(
                        af, bfr[ntt], acc[mt][ntt], 0, 0, 0);
            }
        }
    }

    __syncthreads();
    ushort* sT = sW;

    if (mat < 2) {
#pragma unroll
        for (int mt = 0; mt < 4; ++mt) {
            float4 sc4 = *(const float4*)&sm[ot * 64 + mt * 16 + quad * 4];
            float4 bi4 = *(const float4*)&bm[ot * 64 + mt * 16 + quad * 4];
#pragma unroll
            for (int ntt = 0; ntt < 2; ++ntt) {
                int nrow = wav * 32 + ntt * 16 + l16;
                float v0 = fmaf(acc[mt][ntt][0], sc4.x, bi4.x);
                float v1 = fmaf(acc[mt][ntt][1], sc4.y, bi4.y);
                float v2 = fmaf(acc[mt][ntt][2], sc4.z, bi4.z);
                float v3 = fmaf(acc[mt][ntt][3], sc4.w, bi4.w);
                int cb = (mt * 2 + (quad >> 1)) ^ (nrow & 7);
                *(ushort4*)&sT[nrow * 64 + cb * 8 + (quad & 1) * 4] =
                    pack4bf(v0 > 0.f ? v0 : 0.f, v1 > 0.f ? v1 : 0.f,
                            v2 > 0.f ? v2 : 0.f, v3 > 0.f ? v3 : 0.f);
            }
        }
        __syncthreads();
        ushort* out = (mat == 0) ? qT : kT;
        int rsub = tid >> 3, blk = tid & 7;
#pragma unroll
        for (int p = 0; p < 4; ++p) {
            int row = p * 16 + rsub;
            int4 d = *(const int4*)&sT[row * 64 + ((blk ^ (row & 7)) * 8)];
            *(int4*)&out[((size_t)b * kN + nt * 64 + row) * kC + ot * 64 + blk * 8] = d;
        }
    } else {
#pragma unroll
        for (int ntt = 0; ntt < 2; ++ntt) {
            int orow = wav * 32 + ntt * 16 + l16;
            float sc = sm[ot * 64 + orow], bi = bm[ot * 64 + orow];
#pragma unroll
            for (int mt = 0; mt < 4; ++mt) {
                float v0 = fmaf(acc[mt][ntt][0], sc, bi);
                float v1 = fmaf(acc[mt][ntt][1], sc, bi);
                float v2 = fmaf(acc[mt][ntt][2], sc, bi);
                float v3 = fmaf(acc[mt][ntt][3], sc, bi);
                int cb = (mt * 2 + (quad >> 1)) ^ (orow & 7);
                *(ushort4*)&sT[orow * 64 + cb * 8 + (quad & 1) * 4] =
                    pack4bf(v0 > 0.f ? v0 : 0.f, v1 > 0.f ? v1 : 0.f,
                            v2 > 0.f ? v2 : 0.f, v3 > 0.f ? v3 : 0.f);
            }
        }
        __syncthreads();
        int rsub = tid >> 3, blk = tid & 7;
#pragma unroll
        for (int p = 0; p < 4; ++p) {
            int row = p * 16 + rsub;
            int4 d = *(const int4*)&sT[row * 64 + ((blk ^ (row & 7)) * 8)];
            *(int4*)&vB[((size_t)b * kC + ot * 64 + row) * kN + nt * 64 + blk * 8] = d;
        }
    }
}

// ---------------- MFMA flash attention: 4 waves, Q-tile 128, LDS dbuf ------
// One barrier per 64-key iteration. P region separate (wave-private rows).
__global__ __launch_bounds__(256, 3) void attn_kernel(
    const ushort* __restrict__ qT, const ushort* __restrict__ kT,
    const ushort* __restrict__ vB,
    ushort* __restrict__ Opart, float* __restrict__ Ms, float* __restrict__ Ls)
{
    const int n0 = blockIdx.x * 128;
    const int h  = blockIdx.y;
    const int s  = blockIdx.z & 1;
    const int b  = blockIdx.z >> 1;
    const int tid = threadIdx.x;
    const int lane = tid & 63, wav = tid >> 6;    // 4 waves
    const int quad = lane >> 4, l16 = lane & 15;

    __shared__ __align__(16) ushort sK[2][64 * 64];   // 2 x 8 KB
    __shared__ __align__(16) ushort sV[2][64 * 64];   // 2 x 8 KB
    __shared__ __align__(16) ushort sP[128 * 64];     // 16 KB (also O-transpose)

    const ushort* qTb = qT + (size_t)b * kN * kC;
    const ushort* kTb = kT + (size_t)b * kN * kC;
    const ushort* vbb = vB + ((size_t)b * kC + h * 32) * kN;

    // Q fragments: loop-invariant registers; wave owns 32 n-columns
    bf16x8 qf[2][2];
#pragma unroll
    for (int kk = 0; kk < 2; ++kk)
#pragma unroll
        for (int nt2 = 0; nt2 < 2; ++nt2) {
            int ng = n0 + wav * 32 + nt2 * 16 + l16;
            qf[kk][nt2] = *(const bf16x8*)(qTb + (size_t)ng * kC + h * 32 + kk * 32 + quad * 8);
        }

    f32x4 oacc[4][2];
#pragma unroll
    for (int wt = 0; wt < 4; ++wt)
#pragma unroll
        for (int nt2 = 0; nt2 < 2; ++nt2)
#pragma unroll
            for (int r = 0; r < 4; ++r) oacc[wt][nt2][r] = 0.f;
    float mi[2] = {-1e30f, -1e30f};
    float li[2] = {0.f, 0.f};

    const int mstart = s * kMChunk;
    const int NIT = kMChunk / 64;

    // preload + stage iteration 0 into buffer 0
    int4 kreg[2], vreg[2];
#pragma unroll
    for (int p = 0; p < 2; ++p) {
        int idx = p * 256 + tid, row = idx >> 3, blk = idx & 7;
        kreg[p] = *(const int4*)(kTb + (size_t)(mstart + row) * kC + h * 32 + blk * 8);
        vreg[p] = *(const int4*)(vbb + (size_t)row * kN + mstart + blk * 8);
    }
#pragma unroll
    for (int p = 0; p < 2; ++p) {
        int idx = p * 256 + tid, row = idx >> 3, blk = idx & 7;
        *(int4*)&sK[0][row * 64 + ((blk ^ (row & 7)) * 8)] = kreg[p];
        *(int4*)&sV[0][row * 64 + ((blk ^ (row & 7)) * 8)] = vreg[p];
    }
    __syncthreads();

    for (int it = 0; it < NIT; ++it) {
        const int cur = it & 1;
        const bool more = (it + 1 < NIT);
        if (more) {
            int m1 = mstart + (it + 1) * 64;
#pragma unroll
            for (int p = 0; p < 2; ++p) {
                int idx = p * 256 + tid, row = idx >> 3, blk = idx & 7;
                kreg[p] = *(const int4*)(kTb + (size_t)(m1 + row) * kC + h * 32 + blk * 8);
                vreg[p] = *(const int4*)(vbb + (size_t)row * kN + m1 + blk * 8);
            }
        }

        // S^T[m][n] = sum_w K[w][m] Q[w][n]
        f32x4 sacc[4][2];
#pragma unroll
        for (int mt = 0; mt < 4; ++mt)
#pragma unroll
            for (int nt2 = 0; nt2 < 2; ++nt2)
#pragma unroll
                for (int r = 0; r < 4; ++r) sacc[mt][nt2][r] = 0.f;
#pragma unroll
        for (int kk = 0; kk < 2; ++kk)
#pragma unroll
            for (int mt = 0; mt < 4; ++mt) {
                int row = mt * 16 + l16;
                bf16x8 af = *(const bf16x8*)&sK[cur][row * 64 + (((kk * 4 + quad) ^ (row & 7)) * 8)];
#pragma unroll
                for (int nt2 = 0; nt2 < 2; ++nt2)
                    sacc[mt][nt2] = __builtin_amdgcn_mfma_f32_16x16x32_bf16(
                        af, qf[kk][nt2], sacc[mt][nt2], 0, 0, 0);
            }

        // online softmax; P rows are wave-private in sP (no barrier needed)
#pragma unroll
        for (int nt2 = 0; nt2 < 2; ++nt2) {
            float mloc = -1e30f;
#pragma unroll
            for (int mt = 0; mt < 4; ++mt)
#pragma unroll
                for (int r = 0; r < 4; ++r) mloc = fmaxf(mloc, sacc[mt][nt2][r]);
            mloc = fmaxf(mloc, __shfl_xor(mloc, 16));
            mloc = fmaxf(mloc, __shfl_xor(mloc, 32));
            float mnew = fmaxf(mi[nt2], mloc);
            float al = __expf(mi[nt2] - mnew);
            mi[nt2] = mnew;
            int nrow = wav * 32 + nt2 * 16 + l16;
            float sum = 0.f;
#pragma unroll
            for (int mt = 0; mt < 4; ++mt) {
                float p0 = __expf(sacc[mt][nt2][0] - mnew);
                float p1 = __expf(sacc[mt][nt2][1] - mnew);
                float p2 = __expf(sacc[mt][nt2][2] - mnew);
                float p3 = __expf(sacc[mt][nt2][3] - mnew);
                sum += (p0 + p1) + (p2 + p3);
                int bidx = (mt * 2 + (quad >> 1)) ^ (nrow & 7);
                uint2 pk; pk.x = pack2bf(p0, p1); pk.y = pack2bf(p2, p3);
                *(uint2*)&sP[nrow * 64 + bidx * 8 + (quad & 1) * 4] = pk;
            }
            sum += __shfl_xor(sum, 16);
            sum += __shfl_xor(sum, 32);
            li[nt2] = li[nt2] * al + sum;
#pragma unroll
            for (int wt = 0; wt < 4; ++wt)
#pragma unroll
                for (int r = 0; r < 4; ++r) oacc[wt][nt2][r] *= al;
        }

        // O[w][n] += sum_m V[w][m] P[m][n]
#pragma unroll
        for (int ks = 0; ks < 2; ++ks) {
            bf16x8 pf[2];
#pragma unroll
            for (int nt2 = 0; nt2 < 2; ++nt2) {
                int nr = wav * 32 + nt2 * 16 + l16;
                pf[nt2] = *(const bf16x8*)&sP[nr * 64 + (((ks * 4 + quad) ^ (nr & 7)) * 8)];
            }
#pragma unroll
            for (int wt = 0; wt < 4; ++wt) {
                int wr = wt * 16 + l16;
                bf16x8 vf = *(const bf16x8*)&sV[cur][wr * 64 + (((ks * 4 + quad) ^ (wr & 7)) * 8)];
#pragma unroll
                for (int nt2 = 0; nt2 < 2; ++nt2)
                    oacc[wt][nt2] = __builtin_amdgcn_mfma_f32_16x16x32_bf16(
                        vf, pf[nt2], oacc[wt][nt2], 0, 0, 0);
            }
        }

        if (more) {
            // stage next tile (vmcnt wait lands here, after compute)
#pragma unroll
            for (int p = 0; p < 2; ++p) {
                int idx = p * 256 + tid, row = idx >> 3, blk = idx & 7;
                *(int4*)&sK[1 - cur][row * 64 + ((blk ^ (row & 7)) * 8)] = kreg[p];
                *(int4*)&sV[1 - cur][row * 64 + ((blk ^ (row & 7)) * 8)] = vreg[p];
            }
        }
        __syncthreads();
    }

    // ---- epilogue: stats + LDS-transpose O (own rows) + coalesced store ----
#pragma unroll
    for (int nt2 = 0; nt2 < 2; ++nt2) {
        if (quad == 0) {
            int n = n0 + wav * 32 + nt2 * 16 + l16;
            size_t si = ((size_t)(s * kB + b) * kHeads + h) * kN + n;
            Ms[si] = mi[nt2];
            Ls[si] = li[nt2];
        }
    }
#pragma unroll
    for (int wt = 0; wt < 4; ++wt)
#pragma unroll
        for (int nt2 = 0; nt2 < 2; ++nt2) {
            float inv = 1.f / li[nt2];
            int nrow = wav * 32 + nt2 * 16 + l16;
            int cb = (wt * 2 + (quad >> 1)) ^ (nrow & 7);
            *(ushort4*)&sP[nrow * 64 + cb * 8 + (quad & 1) * 4] =
                pack4bf(oacc[wt][nt2][0] * inv, oacc[wt][nt2][1] * inv,
                        oacc[wt][nt2][2] * inv, oacc[wt][nt2][3] * inv);
        }
    __syncthreads();
    int rsub = tid >> 3, blk = tid & 7;
#pragma unroll
    for (int p = 0; p < 4; ++p) {
        int row = p * 32 + rsub;   // n_local 0..127
        int4 d = *(const int4*)&sP[row * 64 + ((blk ^ (row & 7)) * 8)];
        *(int4*)&Opart[((size_t)s * kB * kN + (size_t)b * kN + n0 + row) * kOC
                       + h * 64 + blk * 8] = d;
    }
}

// ---------------- combine splits -> OT[b][n][c] bf16 -----------------------
__global__ __launch_bounds__(256) void combine_kernel(
    const ushort* __restrict__ Opart, const float* __restrict__ Ms,
    const float* __restrict__ Ls, ushort* __restrict__ OT)
{
    int t = blockIdx.x * 256 + threadIdx.x;
    int bn = t / 112;
    int c4 = (t % 112) * 4;
    int h  = c4 >> 6;
    int b = bn >> 11, n = bn & 2047;
    size_t si = ((size_t)b * kHeads + h) * kN + n;
    size_t soff = (size_t)kB * kHeads * kN;
    float m1 = Ms[si], m2 = Ms[si + soff];
    float l1 = Ls[si], l2 = Ls[si + soff];
    float M = fmaxf(m1, m2);
    float g1 = l1 * __expf(m1 - M), g2 = l2 * __expf(m2 - M);
    float inv = 1.f / (g1 + g2);
    float w1 = g1 * inv, w2 = g2 * inv;
    size_t o1 = (size_t)bn * kOC + c4;
    size_t o2 = o1 + (size_t)kB * kN * kOC;
    ushort4 a = *(const ushort4*)&Opart[o1];
    ushort4 c = *(const ushort4*)&Opart[o2];
    *(ushort4*)&OT[(size_t)bn * kOC + c4] =
        pack4bf(bf2f(a.x) * w1 + bf2f(c.x) * w2, bf2f(a.y) * w1 + bf2f(c.y) * w2,
                bf2f(a.z) * w1 + bf2f(c.z) * w2, bf2f(a.w) * w1 + bf2f(c.w) * w2);
}

// ---------------- final projection, bf16 MFMA ------------------------------
__global__ __launch_bounds__(128) void proj_kernel(
    const ushort* __restrict__ OT, const ushort* __restrict__ Wfb,
    const float* __restrict__ bf_, const float* __restrict__ sf,
    const float* __restrict__ bff, float* __restrict__ out)
{
    const int nt = blockIdx.x;
    const int ot = blockIdx.y;
    const int b  = blockIdx.z;
    __shared__ __align__(16) ushort sA[64 * 64];
    __shared__ __align__(16) ushort sB[64 * 64];
    const int tid = threadIdx.x;
    const int lane = tid & 63, wav = tid >> 6;
    const int quad = lane >> 4, l16 = lane & 15;

    const ushort* Wt = Wfb + (size_t)(ot * 64) * kOC;
    const ushort* Ob = OT + ((size_t)b * kN + nt * 64) * kOC;

    f32x4 acc[4][2];
#pragma unroll
    for (int mt = 0; mt < 4; ++mt)
#pragma unroll
        for (int ntt = 0; ntt < 2; ++ntt)
#pragma unroll
            for (int r = 0; r < 4; ++r) acc[mt][ntt][r] = 0.f;

    for (int k0 = 0; k0 < kOC; k0 += 64) {
        __syncthreads();
#pragma unroll
        for (int p = 0; p < 4; ++p) {
            int idx = p * 128 + tid;
            int row = idx >> 3, blk = idx & 7;
            *(int4*)&sA[row * 64 + ((blk ^ (row & 7)) * 8)] =
                *(const int4*)(Wt + (size_t)row * kOC + k0 + blk * 8);
            *(int4*)&sB[row * 64 + ((blk ^ (row & 7)) * 8)] =
                *(const int4*)(Ob + (size_t)row * kOC + k0 + blk * 8);
        }
        __syncthreads();
#pragma unroll
        for (int ks = 0; ks < 2; ++ks) {
            bf16x8 bfr[2];
#pragma unroll
            for (int ntt = 0; ntt < 2; ++ntt) {
                int row = wav * 32 + ntt * 16 + l16;
                bfr[ntt] = *(const bf16x8*)&sB[row * 64 + (((ks * 4 + quad) ^ (row & 7)) * 8)];
            }
#pragma unroll
            for (int mt = 0; mt < 4; ++mt) {
                int row = mt * 16 + l16;
                bf16x8 af = *(const bf16x8*)&sA[row * 64 + (((ks * 4 + quad) ^ (row & 7)) * 8)];
#pragma unroll
                for (int ntt = 0; ntt < 2; ++ntt)
                    acc[mt][ntt] = __builtin_amdgcn_mfma_f32_16x16x32_bf16(
                        af, bfr[ntt], acc[mt][ntt], 0, 0, 0);
            }
        }
    }
#pragma unroll
    for (int mt = 0; mt < 4; ++mt)
#pragma unroll
        for (int r = 0; r < 4; ++r) {
            int o = ot * 64 + mt * 16 + quad * 4 + r;
            float bfv = bf_[o], sfv = sf[o], bffv = bff[o];
#pragma unroll
            for (int ntt = 0; ntt < 2; ++ntt) {
                int n = nt * 64 + wav * 32 + ntt * 16 + l16;
                float y = fmaf(acc[mt][ntt][r] + bfv, sfv, bffv);
                out[((size_t)b * kC + o) * kN + n] = y > 0.f ? y : 0.f;
            }
        }
}

extern "C" void kernel_launch(void* const* d_in, const int* in_sizes, int n_in,
                              void* d_out, int out_size, void* d_ws, size_t ws_size,
                              hipStream_t stream) {
    const float* x   = (const float*)d_in[0];
    const float* Wq  = (const float*)d_in[1];
    const float* sq  = (const float*)d_in[2];
    const float* bq  = (const float*)d_in[3];
    const float* Wk  = (const float*)d_in[4];
    const float* sk  = (const float*)d_in[5];
    const float* bk  = (const float*)d_in[6];
    const float* Wv  = (const float*)d_in[7];
    const float* sv  = (const float*)d_in[8];
    const float* bv  = (const float*)d_in[9];
    const float* Wf  = (const float*)d_in[10];
    const float* bf_ = (const float*)d_in[11];
    const float* sf  = (const float*)d_in[12];
    const float* bff = (const float*)d_in[13];
    float* out = (float*)d_out;

    char* ws = (char*)d_ws;
    ushort* xT  = (ushort*)(ws);                         // 4,194,304
    ushort* Wqb = (ushort*)(ws + 4194304);               // 131,072
    ushort* Wkb = (ushort*)(ws + 4325376);               // 131,072
    ushort* Wvb = (ushort*)(ws + 4456448);               // 131,072
    ushort* Wfb = (ushort*)(ws + 4587520);               // 229,376
    ushort* qT  = (ushort*)(ws + 4816896);               // 4,194,304
    ushort* kT  = (ushort*)(ws + 9011200);               // 4,194,304
    ushort* vB  = (ushort*)(ws + 13205504);              // 4,194,304
    ushort* Opart = (ushort*)(ws + 17399808);            // 14,680,064
    float*  Ms  = (float*)(ws + 32079872);               // 458,752
    float*  Ls  = (float*)(ws + 32538624);               // 458,752
    ushort* OT  = qT;  // alias: qT/kT dead after attn

    cast_w_kernel<<<dim3(112, 4), 256, 0, stream>>>(Wq, Wk, Wv, Wf, Wqb, Wkb, Wvb, Wfb);
    transpose_kernel<<<dim3(kN / 64, kC / 64, kB), 256, 0, stream>>>(x, xT);
    qkv_kernel<<<dim3(kN / 64, kC / 64, kB * 3), 128, 0, stream>>>(
        xT, Wqb, Wkb, Wvb, sq, bq, sk, bk, sv, bv, qT, kT, vB);
    attn_kernel<<<dim3(kN / 128, kHeads, kB * kSplit), 256, 0, stream>>>(
        qT, kT, vB, Opart, Ms, Ls);
    combine_kernel<<<dim3(kB * kN * 112 / 256), 256, 0, stream>>>(Opart, Ms, Ls, OT);
    proj_kernel<<<dim3(kN / 64, kC / 64, kB), 128, 0, stream>>>(
        OT, Wfb, bf_, sf, bff, out);
}